// Round 16
// baseline (2108.874 us; speedup 1.0000x reference)
//
#include <hip/hip_runtime.h>
#include <math.h>

typedef unsigned short u16;
typedef __attribute__((ext_vector_type(8))) short short8;
typedef __attribute__((ext_vector_type(8))) u16 ushort8_t;
typedef __attribute__((ext_vector_type(4))) u16 ushort4_t;
typedef __attribute__((ext_vector_type(4))) float f32x4;

#define BB 2
#define TT 1024
#define EE 768
#define HH 12
#define HSZ 64
#define LL 12
#define FF 3072
#define VV 50257
#define VPAD 50304
#define MM 2048
#define NQKV 2304
#define QKW 1536     // q|k bf16 buffer width
#define KVB 128      // attention t-tile
#define BK 64

__device__ __forceinline__ float bf2f(u16 u) {
    union { unsigned int i; float f; } c;
    c.i = ((unsigned int)u) << 16;
    return c.f;
}
__device__ __forceinline__ u16 f2bf(float f) {
    unsigned int u = __float_as_uint(f);
    unsigned int r = (u + 0x7FFFu + ((u >> 16) & 1u)) >> 16;
    return (u16)r;
}

__device__ __forceinline__ void gload_lds16(const void* g, void* l) {
    __builtin_amdgcn_global_load_lds(
        (const __attribute__((address_space(1))) unsigned int*)g,
        (__attribute__((address_space(3))) unsigned int*)l,
        16, 0, 0);
}

template<int N> __device__ __forceinline__ void waitcnt_vm() {
    if      constexpr (N == 0)  asm volatile("s_waitcnt vmcnt(0)" ::: "memory");
    else if constexpr (N == 4)  asm volatile("s_waitcnt vmcnt(4)" ::: "memory");
    else if constexpr (N == 6)  asm volatile("s_waitcnt vmcnt(6)" ::: "memory");
    else if constexpr (N == 8)  asm volatile("s_waitcnt vmcnt(8)" ::: "memory");
    else if constexpr (N == 12) asm volatile("s_waitcnt vmcnt(12)" ::: "memory");
    else static_assert(N == 0, "unsupported vmcnt");
}

// bijective XCD-aware block remap (m204); requires gridX*gridY % 8 == 0
__device__ __forceinline__ void xcd_swizzle(int& bx, int& by) {
    int nx = gridDim.x;
    int nwg = nx * gridDim.y;
    int orig = blockIdx.x + blockIdx.y * nx;
    int q = nwg >> 3, r = nwg & 7;
    int xcd = orig & 7, idx = orig >> 3;
    int nf = (xcd < r ? xcd * (q + 1) : r * (q + 1) + (xcd - r) * q) + idx;
    bx = nf % nx;
    by = nf / nx;
}

// ------------------------------------------------------------ weight precast
// All 6 cast jobs in ONE dispatch: blockIdx.y = job, grid-stride within job.
__global__ __launch_bounds__(256)
void cast_all_kernel(const float* __restrict__ qW, const float* __restrict__ kW,
                     const float* __restrict__ vW, const float* __restrict__ fc1w,
                     const float* __restrict__ fc2w, const float* __restrict__ lmw,
                     u16* __restrict__ wqkv, u16* __restrict__ wfc1,
                     u16* __restrict__ wfc2, u16* __restrict__ wlm)
{
    const int j = blockIdx.y;
    const float* s;
    u16* d;
    long total, per, stride;
    switch (j) {
    case 0: s = qW;   d = wqkv;              total = (long)LL * EE * EE; per = (long)EE * EE; stride = (long)NQKV * EE; break;
    case 1: s = kW;   d = wqkv + EE * EE;     total = (long)LL * EE * EE; per = (long)EE * EE; stride = (long)NQKV * EE; break;
    case 2: s = vW;   d = wqkv + 2 * EE * EE; total = (long)LL * EE * EE; per = (long)EE * EE; stride = (long)NQKV * EE; break;
    case 3: s = fc1w; d = wfc1;              total = (long)LL * FF * EE; per = total; stride = total; break;
    case 4: s = fc2w; d = wfc2;              total = (long)LL * EE * FF; per = total; stride = total; break;
    default: s = lmw; d = wlm;               total = (long)VV * EE;      per = total; stride = total; break;
    }
    long step = (long)gridDim.x * blockDim.x * 4;
    for (long i = ((long)blockIdx.x * blockDim.x + threadIdx.x) * 4; i < total; i += step) {
        long layer = i / per;
        long off = i - layer * per;
        float4 v = *reinterpret_cast<const float4*>(s + i);
        ushort4_t o;
        o[0] = f2bf(v.x); o[1] = f2bf(v.y); o[2] = f2bf(v.z); o[3] = f2bf(v.w);
        *reinterpret_cast<ushort4_t*>(d + layer * stride + off) = o;
    }
}

// ---------------------------------------------------------------- embedding
__global__ __launch_bounds__(256)
void embed_kernel(const int* __restrict__ x, const float* __restrict__ tok,
                  const float* __restrict__ pos, float* __restrict__ h,
                  u16* __restrict__ hb)
{
    int row = blockIdx.x;
    int t = row & (TT - 1);
    int id = x[row];
    int tid = threadIdx.x;
    if (tid >= EE / 4) return;
    int col = tid * 4;
    float4 tv = *reinterpret_cast<const float4*>(tok + (size_t)id * EE + col);
    float4 pv = *reinterpret_cast<const float4*>(pos + (size_t)t * EE + col);
    float4 v;
    v.x = tv.x + pv.x; v.y = tv.y + pv.y; v.z = tv.z + pv.z; v.w = tv.w + pv.w;
    *reinterpret_cast<float4*>(h + (size_t)row * EE + col) = v;
    ushort4_t o;
    o[0] = f2bf(v.x); o[1] = f2bf(v.y); o[2] = f2bf(v.z); o[3] = f2bf(v.w);
    *reinterpret_cast<ushort4_t*>(hb + (size_t)row * EE + col) = o;
}

// ---------------------------------------------------------------- add + LN
// hout = LN(hin + add (+ add2)); add2 fuses the split-K partial sum.
__global__ __launch_bounds__(256)
void add_ln_kernel(const float* __restrict__ hin, const float* __restrict__ add,
                   const float* __restrict__ add2,
                   const float* __restrict__ w, const float* __restrict__ bias,
                   float* __restrict__ hout, u16* __restrict__ hbout)
{
    int lane = threadIdx.x & 63, wv = threadIdx.x >> 6;
    int row = blockIdx.x * 4 + wv;
    const float* hp = hin + (size_t)row * EE;
    float x[12];
    float s = 0.f;
#pragma unroll
    for (int c = 0; c < 3; ++c) {
        float4 hv = *reinterpret_cast<const float4*>(hp + c * 256 + lane * 4);
        if (add) {
            float4 av = *reinterpret_cast<const float4*>(add + (size_t)row * EE + c * 256 + lane * 4);
            hv.x += av.x; hv.y += av.y; hv.z += av.z; hv.w += av.w;
        }
        if (add2) {
            float4 av = *reinterpret_cast<const float4*>(add2 + (size_t)row * EE + c * 256 + lane * 4);
            hv.x += av.x; hv.y += av.y; hv.z += av.z; hv.w += av.w;
        }
        x[c * 4 + 0] = hv.x; x[c * 4 + 1] = hv.y; x[c * 4 + 2] = hv.z; x[c * 4 + 3] = hv.w;
        s += hv.x + hv.y + hv.z + hv.w;
    }
#pragma unroll
    for (int o = 32; o > 0; o >>= 1) s += __shfl_xor(s, o);
    float mu = s * (1.0f / EE);
    float vs = 0.f;
#pragma unroll
    for (int i = 0; i < 12; ++i) { float d = x[i] - mu; vs += d * d; }
#pragma unroll
    for (int o = 32; o > 0; o >>= 1) vs += __shfl_xor(vs, o);
    float inv = 1.0f / sqrtf(vs * (1.0f / EE) + 1e-5f);
#pragma unroll
    for (int c = 0; c < 3; ++c) {
        int col = c * 256 + lane * 4;
        float4 wv4 = *reinterpret_cast<const float4*>(w + col);
        float4 bv4 = *reinterpret_cast<const float4*>(bias + col);
        float4 o;
        o.x = (x[c * 4 + 0] - mu) * inv * wv4.x + bv4.x;
        o.y = (x[c * 4 + 1] - mu) * inv * wv4.y + bv4.y;
        o.z = (x[c * 4 + 2] - mu) * inv * wv4.z + bv4.z;
        o.w = (x[c * 4 + 3] - mu) * inv * wv4.w + bv4.w;
        *reinterpret_cast<float4*>(hout + (size_t)row * EE + col) = o;
        ushort4_t ob;
        ob[0] = f2bf(o.x); ob[1] = f2bf(o.y); ob[2] = f2bf(o.z); ob[3] = f2bf(o.w);
        *reinterpret_cast<ushort4_t*>(hbout + (size_t)row * EE + col) = ob;
    }
}

// ---------------------------------------------------------------- GEMM
// Wave grid WM x WN (WM*WN*64 threads), per-wave MR x NR 16x16 fragments.
// Tile (WM*MR*16) x (WN*NR*16), BK=64. DEPTH>1: LDS ring + counted per-wave
// vmcnt (two-barrier, proven); DEPTH==1: single buffer + syncthreads
// (big-grid LM head: occupancy/tile-size win, m132).
// KSPLIT: blockIdx.z halves K; z-half writes Cout + z*MM*Ndim, bias on z==0.
// LDS rule: DEPTH*(BMT+BNT)*BK*2 <= 48KB keeps 3 blocks/CU resident.
enum { EPI_GELU_BF16 = 1, EPI_BIAS_F32 = 2, EPI_F32 = 3, EPI_QKV = 4 };

template<int EPI, bool NGUARD, int DEPTH, int WM, int WN, int MR, int NR, bool KSPLIT = false>
__global__ __launch_bounds__(WM * WN * 64, 2)
void gemm_kernel(const u16* __restrict__ A, const u16* __restrict__ Bw,
                 const float* __restrict__ bias, void* __restrict__ Cout,
                 void* __restrict__ vTout, int Ndim, int Kdim, int Kstride)
{
    constexpr int NW  = WM * WN;
    constexpr int BMT = WM * MR * 16;
    constexpr int BNT = WN * NR * 16;
    constexpr int CA  = BMT / (8 * NW);   // A gload_lds per wave per stage
    constexpr int CB  = BNT / (8 * NW);   // B gload_lds per wave per stage
    constexpr int NLD = CA + CB;
    static_assert(BMT % (8 * NW) == 0 && BNT % (8 * NW) == 0, "stage geom");
    __shared__ u16 As[DEPTH * BMT * BK];
    __shared__ u16 Bs[DEPTH * BNT * BK];
    const int tid = threadIdx.x;
    const int lane = tid & 63;
    const int wid = tid >> 6;
    const int wm = wid / WN, wn = wid % WN;
    int bx, by;
    xcd_swizzle(bx, by);
    const int rowBase = bx * BMT;
    const int colBase = by * BNT;

    const u16* Ab = A + (KSPLIT ? (size_t)blockIdx.z * Kdim : 0);
    const u16* Bb = Bw + (KSPLIT ? (size_t)blockIdx.z * Kdim : 0);

    const int srow = lane >> 3;
    const int scol = ((lane & 7) ^ srow) * 8;   // pre-swizzled global source

#define GSTAGE(k0_, buf_)                                                          \
    {                                                                              \
        _Pragma("unroll")                                                          \
        for (int i_ = 0; i_ < CA; ++i_) {                                          \
            int r0_ = (wid * CA + i_) * 8;                                         \
            gload_lds16(Ab + (size_t)(rowBase + r0_ + srow) * Kstride + (k0_) + scol, \
                        As + (buf_) * (BMT * BK) + r0_ * BK);                      \
        }                                                                          \
        _Pragma("unroll")                                                          \
        for (int i_ = 0; i_ < CB; ++i_) {                                          \
            int r0_ = (wid * CB + i_) * 8;                                         \
            gload_lds16(Bb + (size_t)(colBase + r0_ + srow) * Kstride + (k0_) + scol, \
                        Bs + (buf_) * (BNT * BK) + r0_ * BK);                      \
        }                                                                          \
    }

#define COMPUTE(Asb_, Bsb_)                                                       \
    {                                                                             \
        const int fr = lane & 15;                                                 \
        const int qd = lane >> 4;                                                 \
        _Pragma("unroll")                                                         \
        for (int kk = 0; kk < 2; ++kk) {                                          \
            short8 af[MR], bfr[NR];                                               \
            int goff = (((kk * 4 + qd) ^ (fr & 7))) * 8;                          \
            _Pragma("unroll")                                                     \
            for (int mi = 0; mi < MR; ++mi)                                       \
                af[mi] = *reinterpret_cast<const short8*>(                        \
                    &(Asb_)[(wm * (MR * 16) + mi * 16 + fr) * BK + goff]);        \
            _Pragma("unroll")                                                     \
            for (int ni = 0; ni < NR; ++ni)                                       \
                bfr[ni] = *reinterpret_cast<const short8*>(                       \
                    &(Bsb_)[(wn * (NR * 16) + ni * 16 + fr) * BK + goff]);        \
            _Pragma("unroll")                                                     \
            for (int mi = 0; mi < MR; ++mi)                                       \
                _Pragma("unroll")                                                 \
                for (int ni = 0; ni < NR; ++ni)                                   \
                    acc[mi][ni] = __builtin_amdgcn_mfma_f32_16x16x32_bf16(        \
                        af[mi], bfr[ni], acc[mi][ni], 0, 0, 0);                   \
        }                                                                         \
    }

    f32x4 acc[MR][NR] = {};
    const int nk = Kdim / BK;

    if (DEPTH > 1) {
#pragma unroll
        for (int p = 0; p < DEPTH; ++p) GSTAGE(p * BK, p)
        int cur = 0;
        for (int t = 0; t < nk; ++t) {
            int rem = nk - 1 - t;
            if (rem >= DEPTH - 1)            waitcnt_vm<NLD * (DEPTH - 1)>();
            else if (DEPTH > 2 && rem == 1)  waitcnt_vm<NLD>();
            else                             waitcnt_vm<0>();
            __builtin_amdgcn_s_barrier();          // tile t staged & visible
            const u16* Asb = As + cur * (BMT * BK);
            const u16* Bsb = Bs + cur * (BNT * BK);
            COMPUTE(Asb, Bsb)
            __builtin_amdgcn_s_barrier();          // all waves done reading
            if (t + DEPTH < nk) GSTAGE((t + DEPTH) * BK, cur)
            cur = (cur + 1 == DEPTH) ? 0 : cur + 1;
        }
    } else {
        for (int t = 0; t < nk; ++t) {
            GSTAGE(t * BK, 0)
            __syncthreads();
            COMPUTE(As, Bs)
            __syncthreads();
        }
    }

    if (EPI == EPI_QKV && colBase >= QKW) {
        // V projection: transpose via LDS -> coalesced vT[b][hd][t] writes
        u16* T = Bs;                       // reuse (>= BNT*72 u16)
        __syncthreads();
#pragma unroll
        for (int mi = 0; mi < MR; ++mi)
#pragma unroll
            for (int ni = 0; ni < NR; ++ni)
#pragma unroll
                for (int r = 0; r < 4; ++r) {
                    int lr = wm * (MR * 16) + mi * 16 + (lane >> 4) * 4 + r;
                    int lc = wn * (NR * 16) + ni * 16 + (lane & 15);
                    T[lc * 72 + lr] = f2bf(acc[mi][ni][r]);
                }
        __syncthreads();
        constexpr int SEGS = BMT / 32;
        int hdl = tid / SEGS;
        int seg = (tid % SEGS) * 32;
        if (hdl < BNT) {
            int b_ = rowBase >> 10;
            int t0 = rowBase & (TT - 1);
            u16* dst = (u16*)vTout + ((size_t)b_ * EE + (colBase - QKW) + hdl) * TT + t0 + seg;
            const u16* src = T + hdl * 72 + seg;
#pragma unroll
            for (int j = 0; j < 4; ++j)
                *reinterpret_cast<ushort8_t*>(dst + j * 8) =
                    *reinterpret_cast<const ushort8_t*>(src + j * 8);
        }
        return;
    }

    const size_t zoff = KSPLIT ? (size_t)blockIdx.z * MM * Ndim : 0;
#pragma unroll
    for (int mi = 0; mi < MR; ++mi) {
#pragma unroll
        for (int ni = 0; ni < NR; ++ni) {
#pragma unroll
            for (int r = 0; r < 4; ++r) {
                int row = rowBase + wm * (MR * 16) + mi * 16 + (lane >> 4) * 4 + r;
                int col = colBase + wn * (NR * 16) + ni * 16 + (lane & 15);
                if (NGUARD && col >= Ndim) continue;
                float v = acc[mi][ni][r];
                if (EPI == EPI_GELU_BF16) { v += bias[col]; v = 0.5f * v * (1.0f + erff(v * 0.70710678f)); }
                if (EPI == EPI_BIAS_F32)  { if (!KSPLIT || blockIdx.z == 0) v += bias[col]; }
                size_t idx = (size_t)row * Ndim + col;
                if (EPI == EPI_QKV) {
                    ((u16*)Cout)[(size_t)row * QKW + col] = f2bf(v);
                } else if (EPI == EPI_GELU_BF16) {
                    ((u16*)Cout)[idx] = f2bf(v);
                } else {
                    ((float*)Cout)[zoff + idx] = v;
                }
            }
        }
    }
}

// ---------------------------------------------------------------- flash attention (MFMA)
// No Q/V LDS staging: qkb/vT are L2/L3-resident (9.4 MB/layer) — direct
// global fragment reads (m169 lesson: staging cache-fit data is overhead).
// Waves fully independent (no barriers); only Ps (wave-private) in LDS.
__global__ __launch_bounds__(256)
void attn_kernel(const u16* __restrict__ qkb, const u16* __restrict__ vT,
                 float* __restrict__ aout)
{
    __shared__ u16 Ps[4 * 16 * KVB];    // per-wave [s 16][t 128]

    const int lane = threadIdx.x & 63;
    const int wv = threadIdx.x >> 6;
    int bxs, bys;
    xcd_swizzle(bxs, bys);
    const int js = (gridDim.x - 1) - bxs;          // heavy tiles first
    const int s0 = js * 64;
    const int smax = s0 + 63;
    const int bh = bys;
    const int b = bh / HH, h = bh % HH;
    const int bT = b * TT;
    const float scale = 0.036084392f;   // 1/sqrt(768)

    // persistent K fragments (A operand)
    short8 af[2];
    {
        int srow = bT + s0 + wv * 16 + (lane & 15);
#pragma unroll
        for (int kk = 0; kk < 2; ++kk)
            af[kk] = *reinterpret_cast<const short8*>(
                qkb + (size_t)srow * QKW + EE + h * HSZ + kk * 32 + (lane >> 4) * 8);
    }

    const int ntiles = (s0 + 63) / KVB + 1;
    const u16* qbase = qkb + (size_t)bT * QKW + h * HSZ;       // Q[t] at qbase + t*QKW
    const u16* vbase = vT + ((size_t)b * EE + h * HSZ) * TT;   // V^T[d] at vbase + d*TT

    float m[4], l[4];
    f32x4 oacc[4] = {};
#pragma unroll
    for (int r = 0; r < 4; ++r) { m[r] = -INFINITY; l[r] = 0.f; }

    for (int jt2 = 0; jt2 < ntiles; ++jt2) {
        const int tb = jt2 * KVB;
        const int navail = smax - tb;
        const int nact = min(8, (navail >> 4) + 1);
        const int nkc  = min(4, (navail >> 5) + 1);
        const bool dg = (tb + KVB - 1 > s0);

        // ---- scores: 16 s x 128 t, Q fragments direct from global (L2)
        f32x4 sc[8];
#pragma unroll
        for (int ni = 0; ni < 8; ++ni) {
            if (ni < nact) {
                f32x4 a = {};
                int trow = tb + ni * 16 + (lane & 15);
#pragma unroll
                for (int kk = 0; kk < 2; ++kk) {
                    short8 bq = *reinterpret_cast<const short8*>(
                        qbase + (size_t)trow * QKW + (kk * 4 + (lane >> 4)) * 8);
                    a = __builtin_amdgcn_mfma_f32_16x16x32_bf16(af[kk], bq, a, 0, 0, 0);
                }
                sc[ni] = a;
            } else {
                f32x4 mn = {-1e30f, -1e30f, -1e30f, -1e30f};
                sc[ni] = mn;
            }
        }

        if (dg) {
#pragma unroll
            for (int ni = 0; ni < 8; ++ni)
#pragma unroll
                for (int r = 0; r < 4; ++r) {
                    float sv = sc[ni][r] * scale;
                    int t = tb + ni * 16 + (lane & 15);
                    int s = s0 + wv * 16 + (lane >> 4) * 4 + r;
                    if (t > s) sv = -1e30f;
                    sc[ni][r] = sv;
                }
        } else {
#pragma unroll
            for (int ni = 0; ni < 8; ++ni)
#pragma unroll
                for (int r = 0; r < 4; ++r) sc[ni][r] *= scale;
        }

        // ---- online softmax per s-row
        f32x4 pexp[8];
#pragma unroll
        for (int r = 0; r < 4; ++r) {
            float rm = sc[0][r];
#pragma unroll
            for (int ni = 1; ni < 8; ++ni) rm = fmaxf(rm, sc[ni][r]);
#pragma unroll
            for (int o = 1; o < 16; o <<= 1) rm = fmaxf(rm, __shfl_xor(rm, o));
            float mnew = fmaxf(m[r], rm);
            float alpha = __expf(m[r] - mnew);
            m[r] = mnew;
            float rs = 0.f;
#pragma unroll
            for (int ni = 0; ni < 8; ++ni) {
                float p;
                if (ni < nact) p = __expf(sc[ni][r] - mnew);
                else p = 0.f;
                pexp[ni][r] = p;
                rs += p;
            }
#pragma unroll
            for (int o = 1; o < 16; o <<= 1) rs += __shfl_xor(rs, o);
            l[r] = l[r] * alpha + rs;
#pragma unroll
            for (int dt = 0; dt < 4; ++dt) oacc[dt][r] *= alpha;
        }

        // ---- P -> LDS (bf16, wave-private, 16-unit XOR swizzle)
        const int nst = nkc * 2;
#pragma unroll
        for (int ni = 0; ni < 8; ++ni) {
            if (ni < nst) {
#pragma unroll
                for (int r = 0; r < 4; ++r) {
                    int sl = (lane >> 4) * 4 + r;
                    int tl = ni * 16 + (lane & 15);
                    Ps[wv * (16 * KVB) + sl * KVB + (((tl >> 3) ^ sl) & 15) * 8 + (tl & 7)]
                        = f2bf(pexp[ni][r]);
                }
            }
        }

        // ---- O += P * V : V fragments direct from global (L2)
#pragma unroll
        for (int kc = 0; kc < 4; ++kc) {
            if (kc < nkc) {
                int srow = lane & 15;
                int g = kc * 4 + (lane >> 4);
                short8 pa = *reinterpret_cast<const short8*>(
                    &Ps[wv * (16 * KVB) + srow * KVB + ((g ^ srow) & 15) * 8]);
#pragma unroll
                for (int dt = 0; dt < 4; ++dt) {
                    int drow = dt * 16 + (lane & 15);
                    short8 bv = *reinterpret_cast<const short8*>(
                        vbase + (size_t)drow * TT + tb + (kc * 4 + (lane >> 4)) * 8);
                    oacc[dt] = __builtin_amdgcn_mfma_f32_16x16x32_bf16(pa, bv, oacc[dt], 0, 0, 0);
                }
            }
        }
    }

    float invl[4];
#pragma unroll
    for (int r = 0; r < 4; ++r) invl[r] = 1.0f / l[r];
#pragma unroll
    for (int dt = 0; dt < 4; ++dt)
#pragma unroll
        for (int r = 0; r < 4; ++r) {
            int sg = s0 + wv * 16 + (lane >> 4) * 4 + r;
            aout[(size_t)(bT + sg) * EE + h * HSZ + dt * 16 + (lane & 15)] =
                oacc[dt][r] * invl[r];
        }
}

// ---------------------------------------------------------------- driver
extern "C" void kernel_launch(void* const* d_in, const int* in_sizes, int n_in,
                              void* d_out, int out_size, void* d_ws, size_t ws_size,
                              hipStream_t stream)
{
    const int*   x    = (const int*)d_in[0];
    const float* tok  = (const float*)d_in[1];
    const float* pos  = (const float*)d_in[2];
    const float* qW   = (const float*)d_in[3];
    const float* kW   = (const float*)d_in[4];
    const float* vW   = (const float*)d_in[5];
    const float* ln1w = (const float*)d_in[6];
    const float* ln1b = (const float*)d_in[7];
    const float* fc1w = (const float*)d_in[8];
    const float* fc1b = (const float*)d_in[9];
    const float* fc2w = (const float*)d_in[10];
    const float* fc2b = (const float*)d_in[11];
    const float* ln2w = (const float*)d_in[12];
    const float* ln2b = (const float*)d_in[13];
    const float* lnfw = (const float*)d_in[14];
    const float* lnfb = (const float*)d_in[15];
    const float* lmw  = (const float*)d_in[16];
    float* out = (float*)d_out;

    char* ws = (char*)d_ws;
    u16* wqkv = (u16*)ws;  ws += (size_t)LL * NQKV * EE * 2;
    u16* wfc1 = (u16*)ws;  ws += (size_t)LL * FF * EE * 2;
    u16* wfc2 = (u16*)ws;  ws += (size_t)LL * EE * FF * 2;
    u16* wlm  = (u16*)ws;  ws += (size_t)VPAD * EE * 2;
    float* h    = (float*)ws; ws += (size_t)MM * EE * 4;
    float* tmp  = (float*)ws; ws += (size_t)2 * MM * EE * 4;  // tmp + tmp2 (split-K)
    float* tmp2 = tmp + (size_t)MM * EE;
    u16* qkb = (u16*)ws;      ws += (size_t)MM * QKW * 2;
    u16* vTb = (u16*)ws;      ws += (size_t)BB * EE * TT * 2;
    u16* hb  = (u16*)ws;      ws += (size_t)MM * EE * 2;
    u16* mb  = (u16*)ws;      ws += (size_t)MM * FF * 2;

    dim3 blk(256);

    cast_all_kernel<<<dim3(1024, 6), blk, 0, stream>>>(
        qW, kW, vW, fc1w, fc2w, lmw, wqkv, wfc1, wfc2, wlm);

    embed_kernel<<<MM, blk, 0, stream>>>(x, tok, pos, h, hb);

    dim3 gQKV(MM / 64, NQKV / 128);      // 32 x 18 = 576 blocks
    dim3 gF1(MM / 64, FF / 128);         // 32 x 24 = 768
    dim3 gF2(MM / 64, EE / 64, 2);       // 32 x 12 x 2 = 768 (split-K x2)
    dim3 gV(MM / 128, VPAD / 128);       // 16 x 393 = 6288 (proven 237us config)
    dim3 gAttn(TT / 64, BB * HH);        // 16 x 24 = 384

    for (int l = 0; l < LL; ++l) {
        gemm_kernel<EPI_QKV, false, 2, 2, 2, 2, 4><<<gQKV, blk, 0, stream>>>(
            hb, wqkv + (size_t)l * NQKV * EE, nullptr, qkb, vTb, NQKV, EE, EE);
        attn_kernel<<<gAttn, blk, 0, stream>>>(qkb, vTb, tmp);
        add_ln_kernel<<<MM / 4, blk, 0, stream>>>(h, tmp, nullptr,
                                                  ln1w + l * EE, ln1b + l * EE, h, hb);
        gemm_kernel<EPI_GELU_BF16, false, 2, 2, 2, 2, 4><<<gF1, blk, 0, stream>>>(
            hb, wfc1 + (size_t)l * FF * EE, fc1b + (size_t)l * FF, mb, nullptr, FF, EE, EE);
        gemm_kernel<EPI_BIAS_F32, false, 3, 2, 2, 2, 2, true><<<gF2, blk, 0, stream>>>(
            mb, wfc2 + (size_t)l * EE * FF, fc2b + (size_t)l * EE, tmp, nullptr,
            EE, FF / 2, FF);
        add_ln_kernel<<<MM / 4, blk, 0, stream>>>(h, tmp, tmp2,
                                                  ln2w + l * EE, ln2b + l * EE, h, hb);
    }
    add_ln_kernel<<<MM / 4, blk, 0, stream>>>(h, nullptr, nullptr, lnfw, lnfb, h, hb);
    gemm_kernel<EPI_F32, true, 1, 2, 2, 4, 4><<<gV, blk, 0, stream>>>(
        hb, wlm, nullptr, out, nullptr, VV, EE, EE);
}

// Round 17
// 1731.622 us; speedup vs baseline: 1.2179x; 1.2179x over previous
//
#include <hip/hip_runtime.h>
#include <math.h>

typedef unsigned short u16;
typedef __attribute__((ext_vector_type(8))) short short8;
typedef __attribute__((ext_vector_type(8))) u16 ushort8_t;
typedef __attribute__((ext_vector_type(4))) u16 ushort4_t;
typedef __attribute__((ext_vector_type(4))) float f32x4;

#define BB 2
#define TT 1024
#define EE 768
#define HH 12
#define HSZ 64
#define LL 12
#define FF 3072
#define VV 50257
#define VPAD 50304
#define MM 2048
#define NQKV 2304
#define QKW 1536     // q|k bf16 buffer width
#define KVB 128      // attention t-tile
#define BK 64

__device__ __forceinline__ float bf2f(u16 u) {
    union { unsigned int i; float f; } c;
    c.i = ((unsigned int)u) << 16;
    return c.f;
}
__device__ __forceinline__ u16 f2bf(float f) {
    unsigned int u = __float_as_uint(f);
    unsigned int r = (u + 0x7FFFu + ((u >> 16) & 1u)) >> 16;
    return (u16)r;
}

__device__ __forceinline__ void gload_lds16(const void* g, void* l) {
    __builtin_amdgcn_global_load_lds(
        (const __attribute__((address_space(1))) unsigned int*)g,
        (__attribute__((address_space(3))) unsigned int*)l,
        16, 0, 0);
}

template<int N> __device__ __forceinline__ void waitcnt_vm() {
    if      constexpr (N == 0)  asm volatile("s_waitcnt vmcnt(0)" ::: "memory");
    else if constexpr (N == 4)  asm volatile("s_waitcnt vmcnt(4)" ::: "memory");
    else if constexpr (N == 6)  asm volatile("s_waitcnt vmcnt(6)" ::: "memory");
    else if constexpr (N == 8)  asm volatile("s_waitcnt vmcnt(8)" ::: "memory");
    else if constexpr (N == 12) asm volatile("s_waitcnt vmcnt(12)" ::: "memory");
    else static_assert(N == 0, "unsupported vmcnt");
}

// bijective XCD-aware block remap (m204); requires gridX*gridY % 8 == 0
__device__ __forceinline__ void xcd_swizzle(int& bx, int& by) {
    int nx = gridDim.x;
    int nwg = nx * gridDim.y;
    int orig = blockIdx.x + blockIdx.y * nx;
    int q = nwg >> 3, r = nwg & 7;
    int xcd = orig & 7, idx = orig >> 3;
    int nf = (xcd < r ? xcd * (q + 1) : r * (q + 1) + (xcd - r) * q) + idx;
    bx = nf % nx;
    by = nf / nx;
}

// ------------------------------------------------------------ weight precast
// All 6 cast jobs in ONE dispatch: blockIdx.y = job, grid-stride within job.
__global__ __launch_bounds__(256)
void cast_all_kernel(const float* __restrict__ qW, const float* __restrict__ kW,
                     const float* __restrict__ vW, const float* __restrict__ fc1w,
                     const float* __restrict__ fc2w, const float* __restrict__ lmw,
                     u16* __restrict__ wqkv, u16* __restrict__ wfc1,
                     u16* __restrict__ wfc2, u16* __restrict__ wlm)
{
    const int j = blockIdx.y;
    const float* s;
    u16* d;
    long total, per, stride;
    switch (j) {
    case 0: s = qW;   d = wqkv;              total = (long)LL * EE * EE; per = (long)EE * EE; stride = (long)NQKV * EE; break;
    case 1: s = kW;   d = wqkv + EE * EE;     total = (long)LL * EE * EE; per = (long)EE * EE; stride = (long)NQKV * EE; break;
    case 2: s = vW;   d = wqkv + 2 * EE * EE; total = (long)LL * EE * EE; per = (long)EE * EE; stride = (long)NQKV * EE; break;
    case 3: s = fc1w; d = wfc1;              total = (long)LL * FF * EE; per = total; stride = total; break;
    case 4: s = fc2w; d = wfc2;              total = (long)LL * EE * FF; per = total; stride = total; break;
    default: s = lmw; d = wlm;               total = (long)VV * EE;      per = total; stride = total; break;
    }
    long step = (long)gridDim.x * blockDim.x * 4;
    for (long i = ((long)blockIdx.x * blockDim.x + threadIdx.x) * 4; i < total; i += step) {
        long layer = i / per;
        long off = i - layer * per;
        float4 v = *reinterpret_cast<const float4*>(s + i);
        ushort4_t o;
        o[0] = f2bf(v.x); o[1] = f2bf(v.y); o[2] = f2bf(v.z); o[3] = f2bf(v.w);
        *reinterpret_cast<ushort4_t*>(d + layer * stride + off) = o;
    }
}

// ---------------------------------------------------------------- embedding
__global__ __launch_bounds__(256)
void embed_kernel(const int* __restrict__ x, const float* __restrict__ tok,
                  const float* __restrict__ pos, float* __restrict__ h,
                  u16* __restrict__ hb)
{
    int row = blockIdx.x;
    int t = row & (TT - 1);
    int id = x[row];
    int tid = threadIdx.x;
    if (tid >= EE / 4) return;
    int col = tid * 4;
    float4 tv = *reinterpret_cast<const float4*>(tok + (size_t)id * EE + col);
    float4 pv = *reinterpret_cast<const float4*>(pos + (size_t)t * EE + col);
    float4 v;
    v.x = tv.x + pv.x; v.y = tv.y + pv.y; v.z = tv.z + pv.z; v.w = tv.w + pv.w;
    *reinterpret_cast<float4*>(h + (size_t)row * EE + col) = v;
    ushort4_t o;
    o[0] = f2bf(v.x); o[1] = f2bf(v.y); o[2] = f2bf(v.z); o[3] = f2bf(v.w);
    *reinterpret_cast<ushort4_t*>(hb + (size_t)row * EE + col) = o;
}

// ---------------------------------------------------------------- add + LN
// hout = LN(hin + add (+ add2)); add2 fuses the split-K partial sum.
__global__ __launch_bounds__(256)
void add_ln_kernel(const float* __restrict__ hin, const float* __restrict__ add,
                   const float* __restrict__ add2,
                   const float* __restrict__ w, const float* __restrict__ bias,
                   float* __restrict__ hout, u16* __restrict__ hbout)
{
    int lane = threadIdx.x & 63, wv = threadIdx.x >> 6;
    int row = blockIdx.x * 4 + wv;
    const float* hp = hin + (size_t)row * EE;
    float x[12];
    float s = 0.f;
#pragma unroll
    for (int c = 0; c < 3; ++c) {
        float4 hv = *reinterpret_cast<const float4*>(hp + c * 256 + lane * 4);
        if (add) {
            float4 av = *reinterpret_cast<const float4*>(add + (size_t)row * EE + c * 256 + lane * 4);
            hv.x += av.x; hv.y += av.y; hv.z += av.z; hv.w += av.w;
        }
        if (add2) {
            float4 av = *reinterpret_cast<const float4*>(add2 + (size_t)row * EE + c * 256 + lane * 4);
            hv.x += av.x; hv.y += av.y; hv.z += av.z; hv.w += av.w;
        }
        x[c * 4 + 0] = hv.x; x[c * 4 + 1] = hv.y; x[c * 4 + 2] = hv.z; x[c * 4 + 3] = hv.w;
        s += hv.x + hv.y + hv.z + hv.w;
    }
#pragma unroll
    for (int o = 32; o > 0; o >>= 1) s += __shfl_xor(s, o);
    float mu = s * (1.0f / EE);
    float vs = 0.f;
#pragma unroll
    for (int i = 0; i < 12; ++i) { float d = x[i] - mu; vs += d * d; }
#pragma unroll
    for (int o = 32; o > 0; o >>= 1) vs += __shfl_xor(vs, o);
    float inv = 1.0f / sqrtf(vs * (1.0f / EE) + 1e-5f);
#pragma unroll
    for (int c = 0; c < 3; ++c) {
        int col = c * 256 + lane * 4;
        float4 wv4 = *reinterpret_cast<const float4*>(w + col);
        float4 bv4 = *reinterpret_cast<const float4*>(bias + col);
        float4 o;
        o.x = (x[c * 4 + 0] - mu) * inv * wv4.x + bv4.x;
        o.y = (x[c * 4 + 1] - mu) * inv * wv4.y + bv4.y;
        o.z = (x[c * 4 + 2] - mu) * inv * wv4.z + bv4.z;
        o.w = (x[c * 4 + 3] - mu) * inv * wv4.w + bv4.w;
        *reinterpret_cast<float4*>(hout + (size_t)row * EE + col) = o;
        ushort4_t ob;
        ob[0] = f2bf(o.x); ob[1] = f2bf(o.y); ob[2] = f2bf(o.z); ob[3] = f2bf(o.w);
        *reinterpret_cast<ushort4_t*>(hbout + (size_t)row * EE + col) = ob;
    }
}

// ---------------------------------------------------------------- GEMM
// Wave grid WM x WN (WM*WN*64 threads), per-wave MR x NR 16x16 fragments.
// Tile (WM*MR*16) x (WN*NR*16), BK=64. DEPTH>1: LDS ring + counted per-wave
// vmcnt (two-barrier, proven); DEPTH==1: single buffer + syncthreads
// (big-grid LM head: occupancy/tile-size win, m132).
// KSPLIT: blockIdx.z halves K; z-half writes Cout + z*MM*Ndim, bias on z==0.
// LDS rule: DEPTH*(BMT+BNT)*BK*2 <= 48KB keeps 3 blocks/CU resident.
enum { EPI_GELU_BF16 = 1, EPI_BIAS_F32 = 2, EPI_F32 = 3, EPI_QKV = 4 };

template<int EPI, bool NGUARD, int DEPTH, int WM, int WN, int MR, int NR, bool KSPLIT = false>
__global__ __launch_bounds__(WM * WN * 64, 2)
void gemm_kernel(const u16* __restrict__ A, const u16* __restrict__ Bw,
                 const float* __restrict__ bias, void* __restrict__ Cout,
                 void* __restrict__ vTout, int Ndim, int Kdim, int Kstride)
{
    constexpr int NW  = WM * WN;
    constexpr int BMT = WM * MR * 16;
    constexpr int BNT = WN * NR * 16;
    constexpr int CA  = BMT / (8 * NW);   // A gload_lds per wave per stage
    constexpr int CB  = BNT / (8 * NW);   // B gload_lds per wave per stage
    constexpr int NLD = CA + CB;
    static_assert(BMT % (8 * NW) == 0 && BNT % (8 * NW) == 0, "stage geom");
    __shared__ u16 As[DEPTH * BMT * BK];
    __shared__ u16 Bs[DEPTH * BNT * BK];
    const int tid = threadIdx.x;
    const int lane = tid & 63;
    const int wid = tid >> 6;
    const int wm = wid / WN, wn = wid % WN;
    int bx, by;
    xcd_swizzle(bx, by);
    const int rowBase = bx * BMT;
    const int colBase = by * BNT;

    const u16* Ab = A + (KSPLIT ? (size_t)blockIdx.z * Kdim : 0);
    const u16* Bb = Bw + (KSPLIT ? (size_t)blockIdx.z * Kdim : 0);

    const int srow = lane >> 3;
    const int scol = ((lane & 7) ^ srow) * 8;   // pre-swizzled global source

#define GSTAGE(k0_, buf_)                                                          \
    {                                                                              \
        _Pragma("unroll")                                                          \
        for (int i_ = 0; i_ < CA; ++i_) {                                          \
            int r0_ = (wid * CA + i_) * 8;                                         \
            gload_lds16(Ab + (size_t)(rowBase + r0_ + srow) * Kstride + (k0_) + scol, \
                        As + (buf_) * (BMT * BK) + r0_ * BK);                      \
        }                                                                          \
        _Pragma("unroll")                                                          \
        for (int i_ = 0; i_ < CB; ++i_) {                                          \
            int r0_ = (wid * CB + i_) * 8;                                         \
            gload_lds16(Bb + (size_t)(colBase + r0_ + srow) * Kstride + (k0_) + scol, \
                        Bs + (buf_) * (BNT * BK) + r0_ * BK);                      \
        }                                                                          \
    }

#define COMPUTE(Asb_, Bsb_)                                                       \
    {                                                                             \
        const int fr = lane & 15;                                                 \
        const int qd = lane >> 4;                                                 \
        _Pragma("unroll")                                                         \
        for (int kk = 0; kk < 2; ++kk) {                                          \
            short8 af[MR], bfr[NR];                                               \
            int goff = (((kk * 4 + qd) ^ (fr & 7))) * 8;                          \
            _Pragma("unroll")                                                     \
            for (int mi = 0; mi < MR; ++mi)                                       \
                af[mi] = *reinterpret_cast<const short8*>(                        \
                    &(Asb_)[(wm * (MR * 16) + mi * 16 + fr) * BK + goff]);        \
            _Pragma("unroll")                                                     \
            for (int ni = 0; ni < NR; ++ni)                                       \
                bfr[ni] = *reinterpret_cast<const short8*>(                       \
                    &(Bsb_)[(wn * (NR * 16) + ni * 16 + fr) * BK + goff]);        \
            _Pragma("unroll")                                                     \
            for (int mi = 0; mi < MR; ++mi)                                       \
                _Pragma("unroll")                                                 \
                for (int ni = 0; ni < NR; ++ni)                                   \
                    acc[mi][ni] = __builtin_amdgcn_mfma_f32_16x16x32_bf16(        \
                        af[mi], bfr[ni], acc[mi][ni], 0, 0, 0);                   \
        }                                                                         \
    }

    f32x4 acc[MR][NR] = {};
    const int nk = Kdim / BK;

    if (DEPTH > 1) {
#pragma unroll
        for (int p = 0; p < DEPTH; ++p) GSTAGE(p * BK, p)
        int cur = 0;
        for (int t = 0; t < nk; ++t) {
            int rem = nk - 1 - t;
            if (rem >= DEPTH - 1)            waitcnt_vm<NLD * (DEPTH - 1)>();
            else if (DEPTH > 2 && rem == 1)  waitcnt_vm<NLD>();
            else                             waitcnt_vm<0>();
            __builtin_amdgcn_s_barrier();          // tile t staged & visible
            const u16* Asb = As + cur * (BMT * BK);
            const u16* Bsb = Bs + cur * (BNT * BK);
            COMPUTE(Asb, Bsb)
            __builtin_amdgcn_s_barrier();          // all waves done reading
            if (t + DEPTH < nk) GSTAGE((t + DEPTH) * BK, cur)
            cur = (cur + 1 == DEPTH) ? 0 : cur + 1;
        }
    } else {
        for (int t = 0; t < nk; ++t) {
            GSTAGE(t * BK, 0)
            __syncthreads();
            COMPUTE(As, Bs)
            __syncthreads();
        }
    }

    if (EPI == EPI_QKV && colBase >= QKW) {
        // V projection: transpose via LDS -> coalesced vT[b][hd][t] writes
        u16* T = Bs;                       // reuse (>= BNT*72 u16)
        __syncthreads();
#pragma unroll
        for (int mi = 0; mi < MR; ++mi)
#pragma unroll
            for (int ni = 0; ni < NR; ++ni)
#pragma unroll
                for (int r = 0; r < 4; ++r) {
                    int lr = wm * (MR * 16) + mi * 16 + (lane >> 4) * 4 + r;
                    int lc = wn * (NR * 16) + ni * 16 + (lane & 15);
                    T[lc * 72 + lr] = f2bf(acc[mi][ni][r]);
                }
        __syncthreads();
        constexpr int SEGS = BMT / 32;
        int hdl = tid / SEGS;
        int seg = (tid % SEGS) * 32;
        if (hdl < BNT) {
            int b_ = rowBase >> 10;
            int t0 = rowBase & (TT - 1);
            u16* dst = (u16*)vTout + ((size_t)b_ * EE + (colBase - QKW) + hdl) * TT + t0 + seg;
            const u16* src = T + hdl * 72 + seg;
#pragma unroll
            for (int j = 0; j < 4; ++j)
                *reinterpret_cast<ushort8_t*>(dst + j * 8) =
                    *reinterpret_cast<const ushort8_t*>(src + j * 8);
        }
        return;
    }

    const size_t zoff = KSPLIT ? (size_t)blockIdx.z * MM * Ndim : 0;
#pragma unroll
    for (int mi = 0; mi < MR; ++mi) {
#pragma unroll
        for (int ni = 0; ni < NR; ++ni) {
#pragma unroll
            for (int r = 0; r < 4; ++r) {
                int row = rowBase + wm * (MR * 16) + mi * 16 + (lane >> 4) * 4 + r;
                int col = colBase + wn * (NR * 16) + ni * 16 + (lane & 15);
                if (NGUARD && col >= Ndim) continue;
                float v = acc[mi][ni][r];
                if (EPI == EPI_GELU_BF16) { v += bias[col]; v = 0.5f * v * (1.0f + erff(v * 0.70710678f)); }
                if (EPI == EPI_BIAS_F32)  { if (!KSPLIT || blockIdx.z == 0) v += bias[col]; }
                size_t idx = (size_t)row * Ndim + col;
                if (EPI == EPI_QKV) {
                    ((u16*)Cout)[(size_t)row * QKW + col] = f2bf(v);
                } else if (EPI == EPI_GELU_BF16) {
                    ((u16*)Cout)[idx] = f2bf(v);
                } else {
                    ((float*)Cout)[zoff + idx] = v;
                }
            }
        }
    }
}

// ---------------------------------------------------------------- flash attention (MFMA)
// Staged (round-15 proven): LDS coalesces the strided Q/V panel reads ONCE
// per tile (direct global fragment reads are 16-64 lines/instr — round-16
// regression). XCD-swizzled grid for L2 locality.
__global__ __launch_bounds__(256)
void attn_kernel(const u16* __restrict__ qkb, const u16* __restrict__ vT,
                 float* __restrict__ aout)
{
    __shared__ u16 Qs[2 * KVB * 64];    // [buf][t 128][d 64]
    __shared__ u16 Vs[2 * 64 * KVB];    // [buf][d 64][t 128]
    __shared__ u16 Ps[4 * 16 * KVB];    // per-wave [s 16][t 128]

    const int lane = threadIdx.x & 63;
    const int wv = threadIdx.x >> 6;
    int bxs, bys;
    xcd_swizzle(bxs, bys);
    const int js = (gridDim.x - 1) - bxs;          // heavy tiles first
    const int s0 = js * 64;
    const int smax = s0 + 63;
    const int bh = bys;
    const int b = bh / HH, h = bh % HH;
    const int bT = b * TT;
    const float scale = 0.036084392f;   // 1/sqrt(768)

    short8 af[2];
    {
        int srow = bT + s0 + wv * 16 + (lane & 15);
#pragma unroll
        for (int kk = 0; kk < 2; ++kk)
            af[kk] = *reinterpret_cast<const short8*>(
                qkb + (size_t)srow * QKW + EE + h * HSZ + kk * 32 + (lane >> 4) * 8);
    }

    const int ntiles = (s0 + 63) / KVB + 1;
    const int qrow = lane >> 3;
    const int qu = lane & 7;
    const int vrow = lane >> 4;
    const int vu = lane & 15;

#define ASTAGE(jt2_, buf_)                                                            \
    {                                                                                 \
        int tb_ = (jt2_) * KVB;                                                       \
        _Pragma("unroll")                                                             \
        for (int i_ = 0; i_ < 4; ++i_) {                                              \
            int R0_ = wv * 32 + i_ * 8;                                               \
            int row_ = R0_ + qrow;                                                    \
            gload_lds16(qkb + (size_t)(bT + tb_ + row_) * QKW + h * HSZ               \
                            + ((qu ^ (row_ & 7)) * 8),                                \
                        &Qs[(buf_) * (KVB * 64) + R0_ * 64]);                         \
        }                                                                             \
        _Pragma("unroll")                                                             \
        for (int i_ = 0; i_ < 4; ++i_) {                                              \
            int R0_ = wv * 16 + i_ * 4;                                               \
            int row_ = R0_ + vrow;                                                    \
            gload_lds16(vT + ((size_t)b * EE + h * HSZ + row_) * TT + tb_             \
                            + ((vu ^ (row_ & 15)) * 8),                               \
                        &Vs[(buf_) * (64 * KVB) + R0_ * KVB]);                        \
        }                                                                             \
    }

    ASTAGE(0, 0)

    float m[4], l[4];
    f32x4 oacc[4] = {};
#pragma unroll
    for (int r = 0; r < 4; ++r) { m[r] = -INFINITY; l[r] = 0.f; }

    int cur = 0;
    for (int jt2 = 0; jt2 < ntiles; ++jt2) {
        __syncthreads();
        if (jt2 + 1 < ntiles) ASTAGE(jt2 + 1, cur ^ 1)

        const u16* Qb = &Qs[cur * (KVB * 64)];
        const u16* Vb = &Vs[cur * (64 * KVB)];
        const int tb = jt2 * KVB;
        const int navail = smax - tb;
        const int nact = min(8, (navail >> 4) + 1);
        const int nkc  = min(4, (navail >> 5) + 1);
        const bool dg = (tb + KVB - 1 > s0);

        f32x4 sc[8];
#pragma unroll
        for (int ni = 0; ni < 8; ++ni) {
            if (ni < nact) {
                f32x4 a = {};
                int trow = ni * 16 + (lane & 15);
#pragma unroll
                for (int kk = 0; kk < 2; ++kk) {
                    int g = kk * 4 + (lane >> 4);
                    short8 bq = *reinterpret_cast<const short8*>(
                        &Qb[trow * 64 + ((g ^ (trow & 7)) * 8)]);
                    a = __builtin_amdgcn_mfma_f32_16x16x32_bf16(af[kk], bq, a, 0, 0, 0);
                }
                sc[ni] = a;
            } else {
                f32x4 mn = {-1e30f, -1e30f, -1e30f, -1e30f};
                sc[ni] = mn;
            }
        }

        if (dg) {
#pragma unroll
            for (int ni = 0; ni < 8; ++ni)
#pragma unroll
                for (int r = 0; r < 4; ++r) {
                    float sv = sc[ni][r] * scale;
                    int t = tb + ni * 16 + (lane & 15);
                    int s = s0 + wv * 16 + (lane >> 4) * 4 + r;
                    if (t > s) sv = -1e30f;
                    sc[ni][r] = sv;
                }
        } else {
#pragma unroll
            for (int ni = 0; ni < 8; ++ni)
#pragma unroll
                for (int r = 0; r < 4; ++r) sc[ni][r] *= scale;
        }

        f32x4 pexp[8];
#pragma unroll
        for (int r = 0; r < 4; ++r) {
            float rm = sc[0][r];
#pragma unroll
            for (int ni = 1; ni < 8; ++ni) rm = fmaxf(rm, sc[ni][r]);
#pragma unroll
            for (int o = 1; o < 16; o <<= 1) rm = fmaxf(rm, __shfl_xor(rm, o));
            float mnew = fmaxf(m[r], rm);
            float alpha = __expf(m[r] - mnew);
            m[r] = mnew;
            float rs = 0.f;
#pragma unroll
            for (int ni = 0; ni < 8; ++ni) {
                float p;
                if (ni < nact) p = __expf(sc[ni][r] - mnew);
                else p = 0.f;
                pexp[ni][r] = p;
                rs += p;
            }
#pragma unroll
            for (int o = 1; o < 16; o <<= 1) rs += __shfl_xor(rs, o);
            l[r] = l[r] * alpha + rs;
#pragma unroll
            for (int dt = 0; dt < 4; ++dt) oacc[dt][r] *= alpha;
        }

        const int nst = nkc * 2;
#pragma unroll
        for (int ni = 0; ni < 8; ++ni) {
            if (ni < nst) {
#pragma unroll
                for (int r = 0; r < 4; ++r) {
                    int sl = (lane >> 4) * 4 + r;
                    int tl = ni * 16 + (lane & 15);
                    Ps[wv * (16 * KVB) + sl * KVB + (((tl >> 3) ^ sl) & 15) * 8 + (tl & 7)]
                        = f2bf(pexp[ni][r]);
                }
            }
        }

#pragma unroll
        for (int kc = 0; kc < 4; ++kc) {
            if (kc < nkc) {
                int srow = lane & 15;
                int g = kc * 4 + (lane >> 4);
                short8 pa = *reinterpret_cast<const short8*>(
                    &Ps[wv * (16 * KVB) + srow * KVB + ((g ^ srow) & 15) * 8]);
#pragma unroll
                for (int dt = 0; dt < 4; ++dt) {
                    int drow = dt * 16 + (lane & 15);
                    short8 bv = *reinterpret_cast<const short8*>(
                        &Vb[drow * KVB + (((kc * 4 + (lane >> 4)) ^ drow) & 15) * 8]);
                    oacc[dt] = __builtin_amdgcn_mfma_f32_16x16x32_bf16(pa, bv, oacc[dt], 0, 0, 0);
                }
            }
        }
        cur ^= 1;
    }

    float invl[4];
#pragma unroll
    for (int r = 0; r < 4; ++r) invl[r] = 1.0f / l[r];
#pragma unroll
    for (int dt = 0; dt < 4; ++dt)
#pragma unroll
        for (int r = 0; r < 4; ++r) {
            int sg = s0 + wv * 16 + (lane >> 4) * 4 + r;
            aout[(size_t)(bT + sg) * EE + h * HSZ + dt * 16 + (lane & 15)] =
                oacc[dt][r] * invl[r];
        }
}

// ---------------------------------------------------------------- driver
extern "C" void kernel_launch(void* const* d_in, const int* in_sizes, int n_in,
                              void* d_out, int out_size, void* d_ws, size_t ws_size,
                              hipStream_t stream)
{
    const int*   x    = (const int*)d_in[0];
    const float* tok  = (const float*)d_in[1];
    const float* pos  = (const float*)d_in[2];
    const float* qW   = (const float*)d_in[3];
    const float* kW   = (const float*)d_in[4];
    const float* vW   = (const float*)d_in[5];
    const float* ln1w = (const float*)d_in[6];
    const float* ln1b = (const float*)d_in[7];
    const float* fc1w = (const float*)d_in[8];
    const float* fc1b = (const float*)d_in[9];
    const float* fc2w = (const float*)d_in[10];
    const float* fc2b = (const float*)d_in[11];
    const float* ln2w = (const float*)d_in[12];
    const float* ln2b = (const float*)d_in[13];
    const float* lnfw = (const float*)d_in[14];
    const float* lnfb = (const float*)d_in[15];
    const float* lmw  = (const float*)d_in[16];
    float* out = (float*)d_out;

    char* ws = (char*)d_ws;
    u16* wqkv = (u16*)ws;  ws += (size_t)LL * NQKV * EE * 2;
    u16* wfc1 = (u16*)ws;  ws += (size_t)LL * FF * EE * 2;
    u16* wfc2 = (u16*)ws;  ws += (size_t)LL * EE * FF * 2;
    u16* wlm  = (u16*)ws;  ws += (size_t)VPAD * EE * 2;
    float* h    = (float*)ws; ws += (size_t)MM * EE * 4;
    float* tmp  = (float*)ws; ws += (size_t)2 * MM * EE * 4;  // tmp + tmp2 (split-K)
    float* tmp2 = tmp + (size_t)MM * EE;
    u16* qkb = (u16*)ws;      ws += (size_t)MM * QKW * 2;
    u16* vTb = (u16*)ws;      ws += (size_t)BB * EE * TT * 2;
    u16* hb  = (u16*)ws;      ws += (size_t)MM * EE * 2;
    u16* mb  = (u16*)ws;      ws += (size_t)MM * FF * 2;

    dim3 blk(256);

    cast_all_kernel<<<dim3(1024, 6), blk, 0, stream>>>(
        qW, kW, vW, fc1w, fc2w, lmw, wqkv, wfc1, wfc2, wlm);

    embed_kernel<<<MM, blk, 0, stream>>>(x, tok, pos, h, hb);

    dim3 gQKV(MM / 64, NQKV / 128);      // 32 x 18 = 576 blocks
    dim3 gF1(MM / 64, FF / 128);         // 32 x 24 = 768
    dim3 gF2(MM / 64, EE / 64, 2);       // 32 x 12 x 2 = 768 (split-K x2)
    dim3 gV(MM / 128, VPAD / 128);       // 16 x 393 = 6288 (proven 237us config)
    dim3 gAttn(TT / 64, BB * HH);        // 16 x 24 = 384

    for (int l = 0; l < LL; ++l) {
        gemm_kernel<EPI_QKV, false, 2, 2, 2, 2, 4><<<gQKV, blk, 0, stream>>>(
            hb, wqkv + (size_t)l * NQKV * EE, nullptr, qkb, vTb, NQKV, EE, EE);
        attn_kernel<<<gAttn, blk, 0, stream>>>(qkb, vTb, tmp);
        add_ln_kernel<<<MM / 4, blk, 0, stream>>>(h, tmp, nullptr,
                                                  ln1w + l * EE, ln1b + l * EE, h, hb);
        gemm_kernel<EPI_GELU_BF16, false, 2, 2, 2, 2, 4><<<gF1, blk, 0, stream>>>(
            hb, wfc1 + (size_t)l * FF * EE, fc1b + (size_t)l * FF, mb, nullptr, FF, EE, EE);
        gemm_kernel<EPI_BIAS_F32, false, 3, 2, 2, 2, 2, true><<<gF2, blk, 0, stream>>>(
            mb, wfc2 + (size_t)l * EE * FF, fc2b + (size_t)l * EE, tmp, nullptr,
            EE, FF / 2, FF);
        add_ln_kernel<<<MM / 4, blk, 0, stream>>>(h, tmp, tmp2,
                                                  ln2w + l * EE, ln2b + l * EE, h, hb);
    }
    add_ln_kernel<<<MM / 4, blk, 0, stream>>>(h, nullptr, nullptr, lnfw, lnfb, h, hb);
    gemm_kernel<EPI_F32, true, 1, 2, 2, 4, 4><<<gV, blk, 0, stream>>>(
        hb, wlm, nullptr, out, nullptr, VV, EE, EE);
}